// Round 2
// baseline (1848.809 us; speedup 1.0000x reference)
//
#include <hip/hip_runtime.h>

// GNN forward for MI355X.
//  - counting-sort edges by receiver (hist/scan/scatter) once per call
//  - edge first-layer decomposed: P_s = h@Ws, P_r = h@Wr (node-level dual GEMM),
//    per-edge: t = P_s[s]+P_r[r]+xe@We+b1 computed in MFMA C-layout registers
//    (C-layout ushort gathers), silu, ONE bf16 LDS write (layout transition),
//    msg = silu(t @ W2 + b2) via MFMA, then in-register segmented reduce over
//    sorted receivers -> coalesced fp32 atomics. Zero barriers in tile loop
//    (each wave owns its 16 sT rows).

typedef short bf16x8 __attribute__((ext_vector_type(8)));
typedef float f32x4 __attribute__((ext_vector_type(4)));

union U8 { bf16x8 v; unsigned short u[8]; };

__device__ __forceinline__ float bf2f(unsigned short u) {
    union { unsigned int i; float f; } x; x.i = ((unsigned int)u) << 16; return x.f;
}
__device__ __forceinline__ unsigned short f2bf(float f) {
    union { float f; unsigned int i; } x; x.f = f;
    unsigned int r = x.i + 0x7FFFu + ((x.i >> 16) & 1u);
    return (unsigned short)(r >> 16);
}
__device__ __forceinline__ float siluf(float x) { return x / (1.0f + __expf(-x)); }

// ---------------- setup: counting sort by receiver ----------------
__global__ void k_hist(const int* __restrict__ recv, int* __restrict__ counts, int E) {
    int i = blockIdx.x * 256 + threadIdx.x;
    if (i < E) atomicAdd(&counts[recv[i]], 1);
}

__global__ void k_scan(const int* __restrict__ counts, int* __restrict__ offsets, int n) {
    __shared__ int buf[1024];
    __shared__ int carry;
    if (threadIdx.x == 0) carry = 0;
    __syncthreads();
    for (int base = 0; base < n; base += 1024) {
        int i = base + (int)threadIdx.x;
        int v = (i < n) ? counts[i] : 0;
        buf[threadIdx.x] = v;
        __syncthreads();
        for (int off = 1; off < 1024; off <<= 1) {
            int t = 0;
            if ((int)threadIdx.x >= off) t = buf[threadIdx.x - off];
            __syncthreads();
            if ((int)threadIdx.x >= off) buf[threadIdx.x] += t;
            __syncthreads();
        }
        if (i < n) offsets[i] = carry + buf[threadIdx.x] - v;
        __syncthreads();
        if (threadIdx.x == 0) carry += buf[1023];
        __syncthreads();
    }
    if (threadIdx.x == 0) offsets[n] = carry;
}

__global__ void k_scatter(const int* __restrict__ send, const int* __restrict__ recv,
                          const int* __restrict__ offsets, int* __restrict__ cursor,
                          int* __restrict__ ss, int* __restrict__ sr,
                          int* __restrict__ perm, int E) {
    int i = blockIdx.x * 256 + threadIdx.x;
    if (i < E) {
        int r = recv[i];
        int pos = offsets[r] + atomicAdd(&cursor[r], 1);
        ss[pos] = send[i];
        sr[pos] = r;
        perm[pos] = i;
    }
}

__global__ void k_permute_xe(const float* __restrict__ xe, const int* __restrict__ perm,
                             unsigned short* __restrict__ out, int E) {
    int t = blockIdx.x * 256 + threadIdx.x;
    if (t < E * 4) {
        int pos = t >> 2, q = t & 3;
        int e = perm[pos];
        float4 v = *(const float4*)(xe + (size_t)e * 16 + q * 4);
        ushort4 o;
        o.x = f2bf(v.x); o.y = f2bf(v.y); o.z = f2bf(v.z); o.w = f2bf(v.w);
        *(ushort4*)(out + (size_t)pos * 16 + q * 4) = o;
    }
}

// ---------------- embed stage 1 (K=16, VALU) ----------------
__global__ __launch_bounds__(256) void k_embed1(const float* __restrict__ x,
                                                const float* __restrict__ w1,
                                                const float* __restrict__ b1,
                                                unsigned short* __restrict__ out, int N) {
    int idx = blockIdx.x * 256 + threadIdx.x;
    int n = idx >> 6, lane = idx & 63;
    if (n >= N) return;
    const float* xr = x + (size_t)n * 16;
    float xv[16];
#pragma unroll
    for (int k = 0; k < 16; k += 4) {
        float4 v = *(const float4*)(xr + k);
        xv[k] = v.x; xv[k + 1] = v.y; xv[k + 2] = v.z; xv[k + 3] = v.w;
    }
    int c0 = lane * 2;
    float a0 = b1[c0], a1 = b1[c0 + 1];
#pragma unroll
    for (int k = 0; k < 16; ++k) {
        float2 w = *(const float2*)(w1 + k * 128 + c0);
        a0 += xv[k] * w.x; a1 += xv[k] * w.y;
    }
    unsigned int pk = (unsigned int)f2bf(siluf(a0)) | ((unsigned int)f2bf(siluf(a1)) << 16);
    *(unsigned int*)(out + (size_t)n * 128 + c0) = pk;
}

// ---------------- generic node GEMM: out = act(A1@W1 [+ A2@W2] + b) ----------------
__global__ __launch_bounds__(256) void k_gemm128(
    const unsigned short* __restrict__ A1, const float* __restrict__ W1,
    const float* __restrict__ A2f, const float* __restrict__ W2,
    const float* __restrict__ bias, int M, int act,
    unsigned short* __restrict__ outB, float* __restrict__ outF) {
    __shared__ unsigned short sW[128 * 136];
    int tid = threadIdx.x, lane = tid & 63, w = tid >> 6;
    int r0 = blockIdx.x * 64 + w * 16;
    int colb = lane & 15, kg = lane >> 4;
    int row = r0 + colb;
    bool rv = row < M;
    f32x4 C[8];
#pragma unroll
    for (int cf = 0; cf < 8; ++cf) C[cf] = (f32x4){0.f, 0.f, 0.f, 0.f};
    int npass = (W2 != nullptr) ? 2 : 1;
    for (int pass = 0; pass < npass; ++pass) {
        const float* W = pass ? W2 : W1;
        __syncthreads();
        for (int i = tid; i < 16384; i += 256) {
            int k = i >> 7, c = i & 127;
            sW[c * 136 + k] = f2bf(W[i]);
        }
        __syncthreads();
        bf16x8 A[4];
        if (pass == 0) {
#pragma unroll
            for (int ks = 0; ks < 4; ++ks) {
                if (rv) A[ks] = *(const bf16x8*)(A1 + (size_t)row * 128 + ks * 32 + kg * 8);
                else { U8 z; for (int i = 0; i < 8; ++i) z.u[i] = 0; A[ks] = z.v; }
            }
        } else {
#pragma unroll
            for (int ks = 0; ks < 4; ++ks) {
                U8 t;
                if (rv) {
                    const float* p = A2f + (size_t)row * 128 + ks * 32 + kg * 8;
#pragma unroll
                    for (int i = 0; i < 8; ++i) t.u[i] = f2bf(p[i]);
                } else {
                    for (int i = 0; i < 8; ++i) t.u[i] = 0;
                }
                A[ks] = t.v;
            }
        }
#pragma unroll
        for (int ks = 0; ks < 4; ++ks) {
#pragma unroll
            for (int cf = 0; cf < 8; ++cf) {
                bf16x8 B = *(const bf16x8*)(&sW[(colb + 16 * cf) * 136 + ks * 32 + kg * 8]);
                C[cf] = __builtin_amdgcn_mfma_f32_16x16x32_bf16(A[ks], B, C[cf], 0, 0, 0);
            }
        }
    }
    int rb = r0 + kg * 4;
#pragma unroll
    for (int cf = 0; cf < 8; ++cf) {
        int col = colb + 16 * cf;
        float bb = bias ? bias[col] : 0.f;
#pragma unroll
        for (int j = 0; j < 4; ++j) {
            int r = rb + j;
            if (r < M) {
                float v = C[cf][j] + bb;
                if (act) v = siluf(v);
                if (outB) outB[(size_t)r * 128 + col] = f2bf(v);
                else outF[(size_t)r * 128 + col] = v;
            }
        }
    }
}

// ---------------- dual-output GEMM: outA = A@Wa, outB = A@Wb (no bias/act) ----------------
__global__ __launch_bounds__(256) void k_gemm_dual(
    const unsigned short* __restrict__ A1, const float* __restrict__ Wa,
    const float* __restrict__ Wb,
    unsigned short* __restrict__ outA, unsigned short* __restrict__ outB, int M) {
    __shared__ unsigned short sW[128 * 136];
    int tid = threadIdx.x, lane = tid & 63, w = tid >> 6;
    int r0 = blockIdx.x * 64 + w * 16;
    int colb = lane & 15, kg = lane >> 4;
    int row = r0 + colb;
    bool rv = row < M;
    int rb = r0 + kg * 4;
    bf16x8 A[4];
#pragma unroll
    for (int ks = 0; ks < 4; ++ks) {
        if (rv) A[ks] = *(const bf16x8*)(A1 + (size_t)row * 128 + ks * 32 + kg * 8);
        else { U8 z; for (int i = 0; i < 8; ++i) z.u[i] = 0; A[ks] = z.v; }
    }
    for (int pass = 0; pass < 2; ++pass) {
        const float* W = pass ? Wb : Wa;
        unsigned short* out = pass ? outB : outA;
        __syncthreads();
        for (int i = tid; i < 16384; i += 256) {
            int k = i >> 7, c = i & 127;
            sW[c * 136 + k] = f2bf(W[i]);
        }
        __syncthreads();
        f32x4 C[8];
#pragma unroll
        for (int cf = 0; cf < 8; ++cf) C[cf] = (f32x4){0.f, 0.f, 0.f, 0.f};
#pragma unroll
        for (int ks = 0; ks < 4; ++ks) {
#pragma unroll
            for (int cf = 0; cf < 8; ++cf) {
                bf16x8 B = *(const bf16x8*)(&sW[(colb + 16 * cf) * 136 + ks * 32 + kg * 8]);
                C[cf] = __builtin_amdgcn_mfma_f32_16x16x32_bf16(A[ks], B, C[cf], 0, 0, 0);
            }
        }
#pragma unroll
        for (int cf = 0; cf < 8; ++cf) {
            int col = colb + 16 * cf;
#pragma unroll
            for (int j = 0; j < 4; ++j) {
                int r = rb + j;
                if (r < M) out[(size_t)r * 128 + col] = f2bf(C[cf][j]);
            }
        }
    }
}

// ---------------- fused edge kernel (barrier-free tile loop) ----------------
__global__ __launch_bounds__(256, 3) void k_edge(
    const unsigned short* __restrict__ Ps, const unsigned short* __restrict__ Pr,
    const unsigned short* __restrict__ xes,
    const int* __restrict__ ssend, const int* __restrict__ srecv,
    const float* __restrict__ We, const float* __restrict__ b1,
    const float* __restrict__ W2, const float* __restrict__ b2,
    float* __restrict__ aggr, int E) {
    __shared__ unsigned short sW2[128 * 136];  // W2^T staged bf16
    __shared__ unsigned short sT[64 * 136];    // per-wave-private 16-row stripes
    int tid = threadIdx.x, lane = tid & 63, w = tid >> 6;
    int colb = lane & 15, kg = lane >> 4;

    for (int i = tid; i < 16384; i += 256) {
        int k = i >> 7, c = i & 127;
        sW2[c * 136 + k] = f2bf(W2[i]);
    }
    // We (16x128) B-fragments in registers, zero-padded to K=32
    bf16x8 WeB[8];
#pragma unroll
    for (int cf = 0; cf < 8; ++cf) {
        U8 t;
#pragma unroll
        for (int i = 0; i < 8; ++i) {
            int k = kg * 8 + i;
            t.u[i] = (k < 16) ? f2bf(We[k * 128 + colb + 16 * cf]) : (unsigned short)0;
        }
        WeB[cf] = t.v;
    }
    float b1v[8], b2v[8];
#pragma unroll
    for (int cf = 0; cf < 8; ++cf) {
        b1v[cf] = b1[colb + 16 * cf];
        b2v[cf] = b2[colb + 16 * cf];
    }
    __syncthreads();  // sW2 ready; no barriers after this point

    int ntiles = E >> 6;
    int R0 = w * 16;
    int rb = R0 + kg * 4;
    for (int tile = blockIdx.x; tile < ntiles; tile += gridDim.x) {
        int e0 = tile << 6;
        int eb = e0 + rb;
        int4 s4 = *(const int4*)(ssend + eb);
        int4 r4 = *(const int4*)(srecv + eb);
        // MFMA-1: xe @ We (A straight from global, K=16 zero-padded)
        bf16x8 Axe;
        if (kg < 2) Axe = *(const bf16x8*)(xes + (size_t)(e0 + R0 + colb) * 16 + kg * 8);
        else { U8 z; for (int i = 0; i < 8; ++i) z.u[i] = 0; Axe = z.v; }
        f32x4 xc[8];
#pragma unroll
        for (int cf = 0; cf < 8; ++cf) {
            f32x4 z = {0.f, 0.f, 0.f, 0.f};
            xc[cf] = __builtin_amdgcn_mfma_f32_16x16x32_bf16(Axe, WeB[cf], z, 0, 0, 0);
        }
        // gather P_s,P_r in C-layout, merge+silu in regs, single bf16 LDS write
#pragma unroll
        for (int j = 0; j < 4; ++j) {
            int s = (j == 0) ? s4.x : (j == 1) ? s4.y : (j == 2) ? s4.z : s4.w;
            int r = (j == 0) ? r4.x : (j == 1) ? r4.y : (j == 2) ? r4.z : r4.w;
            const unsigned short* ps = Ps + (size_t)s * 128 + colb;
            const unsigned short* pr = Pr + (size_t)r * 128 + colb;
            unsigned short* st = sT + (rb + j) * 136 + colb;
#pragma unroll
            for (int cf = 0; cf < 8; ++cf) {
                float v = bf2f(ps[16 * cf]) + bf2f(pr[16 * cf]) + b1v[cf] + xc[cf][j];
                st[16 * cf] = f2bf(siluf(v));
            }
        }
        // wave-local write->read ordering (no cross-wave sharing of sT rows)
        asm volatile("s_waitcnt lgkmcnt(0)" ::: "memory");
        __builtin_amdgcn_sched_barrier(0);
        // MFMA-2: msg = silu(u @ W2 + b2)
        bf16x8 A2[4];
#pragma unroll
        for (int ks = 0; ks < 4; ++ks)
            A2[ks] = *(const bf16x8*)(sT + (R0 + colb) * 136 + ks * 32 + kg * 8);
        f32x4 m[8];
#pragma unroll
        for (int cf = 0; cf < 8; ++cf) m[cf] = (f32x4){0.f, 0.f, 0.f, 0.f};
#pragma unroll
        for (int ks = 0; ks < 4; ++ks) {
#pragma unroll
            for (int cf = 0; cf < 8; ++cf) {
                bf16x8 B = *(const bf16x8*)(sW2 + (colb + 16 * cf) * 136 + ks * 32 + kg * 8);
                m[cf] = __builtin_amdgcn_mfma_f32_16x16x32_bf16(A2[ks], B, m[cf], 0, 0, 0);
            }
        }
        // epilogue: bias+silu, in-lane segmented reduce over 4 sorted rows, atomics
        bool c1 = (r4.y == r4.x), c2 = (r4.z == r4.y), c3 = (r4.w == r4.z);
#pragma unroll
        for (int cf = 0; cf < 8; ++cf) {
            int col = colb + 16 * cf;
            float m0 = siluf(m[cf][0] + b2v[cf]);
            float m1 = siluf(m[cf][1] + b2v[cf]);
            float m2 = siluf(m[cf][2] + b2v[cf]);
            float m3 = siluf(m[cf][3] + b2v[cf]);
            float acc = m0;
            if (c1) acc += m1;
            else { atomicAdd(&aggr[(size_t)r4.x * 128 + col], acc); acc = m1; }
            if (c2) acc += m2;
            else { atomicAdd(&aggr[(size_t)r4.y * 128 + col], acc); acc = m2; }
            if (c3) acc += m3;
            else { atomicAdd(&aggr[(size_t)r4.z * 128 + col], acc); acc = m3; }
            atomicAdd(&aggr[(size_t)r4.w * 128 + col], acc);
        }
    }
}

// ---------------- pooling (batch sorted -> contiguous graph ranges) ----------------
__device__ __forceinline__ int lowerb(const int* a, int n, int v) {
    int lo = 0, hi = n;
    while (lo < hi) { int mid = (lo + hi) >> 1; if (a[mid] < v) lo = mid + 1; else hi = mid; }
    return lo;
}

__global__ __launch_bounds__(128) void k_pool(const float* __restrict__ hpr,
                                              const int* __restrict__ batch,
                                              float* __restrict__ pooled, int N) {
    __shared__ int s_lo, s_hi;
    int g = blockIdx.x;
    if (threadIdx.x == 0) { s_lo = lowerb(batch, N, g); s_hi = lowerb(batch, N, g + 1); }
    __syncthreads();
    int c = threadIdx.x;
    float acc = 0.f;
    for (int r = s_lo; r < s_hi; ++r) acc += hpr[(size_t)r * 128 + c];
    pooled[(size_t)g * 128 + c] = acc;
}

__global__ __launch_bounds__(128) void k_readout(const float* __restrict__ pooled,
                                                 const float* __restrict__ w1,
                                                 const float* __restrict__ b1,
                                                 const float* __restrict__ w2,
                                                 const float* __restrict__ b2,
                                                 float* __restrict__ out) {
    __shared__ float sp[128];
    __shared__ float sred[2];
    int g = blockIdx.x, t = threadIdx.x;
    sp[t] = pooled[(size_t)g * 128 + t];
    __syncthreads();
    float acc = b1[t];
    for (int k = 0; k < 128; ++k) acc += sp[k] * w1[k * 128 + t];
    float val = siluf(acc) * w2[t];
#pragma unroll
    for (int off = 32; off; off >>= 1) val += __shfl_down(val, off);
    if ((t & 63) == 0) sred[t >> 6] = val;
    __syncthreads();
    if (t == 0) out[g] = sred[0] + sred[1] + b2[0];
}

// ---------------- host launcher ----------------
extern "C" void kernel_launch(void* const* d_in, const int* in_sizes, int n_in,
                              void* d_out, int out_size, void* d_ws, size_t ws_size,
                              hipStream_t stream) {
    const float* x_nodes = (const float*)d_in[0];
    const float* x_edges = (const float*)d_in[1];
    const int* edge_index = (const int*)d_in[2];
    const int* batch = (const int*)d_in[3];
    const float* emb_w1 = (const float*)d_in[4];
    const float* emb_b1 = (const float*)d_in[5];
    const float* emb_w2 = (const float*)d_in[6];
    const float* emb_b2 = (const float*)d_in[7];
    const float* ew1 = (const float*)d_in[8];
    const float* eb1 = (const float*)d_in[9];
    const float* ew2 = (const float*)d_in[10];
    const float* eb2 = (const float*)d_in[11];
    const float* nw1 = (const float*)d_in[12];
    const float* nb1 = (const float*)d_in[13];
    const float* nw2 = (const float*)d_in[14];
    const float* nb2 = (const float*)d_in[15];
    const float* pr_w1 = (const float*)d_in[16];
    const float* pr_b1 = (const float*)d_in[17];
    const float* pr_w2 = (const float*)d_in[18];
    const float* pr_b2 = (const float*)d_in[19];
    const float* ro_w1 = (const float*)d_in[20];
    const float* ro_b1 = (const float*)d_in[21];
    const float* ro_w2 = (const float*)d_in[22];
    const float* ro_b2 = (const float*)d_in[23];

    const int N = in_sizes[0] / 16;
    const int E = in_sizes[1] / 16;
    const int G = 512;
    const int L = 4;

    char* p = (char*)d_ws;
    auto alloc = [&](size_t bytes) {
        void* r = p;
        p += (bytes + 255) & ~(size_t)255;
        return r;
    };
    int* counts = (int*)alloc((size_t)N * 4);
    int* cursor = (int*)alloc((size_t)N * 4);
    int* offsets = (int*)alloc((size_t)(N + 1) * 4);
    int* ss = (int*)alloc((size_t)E * 4);
    int* sr = (int*)alloc((size_t)E * 4);
    int* perm = (int*)alloc((size_t)E * 4);
    unsigned short* xes = (unsigned short*)alloc((size_t)E * 16 * 2);
    unsigned short* h = (unsigned short*)alloc((size_t)N * 128 * 2);
    unsigned short* t0 = (unsigned short*)alloc((size_t)N * 128 * 2);
    unsigned short* Ps = (unsigned short*)alloc((size_t)N * 128 * 2);
    unsigned short* Pr = (unsigned short*)alloc((size_t)N * 128 * 2);
    float* aggr = (float*)alloc((size_t)N * 128 * 4);
    float* hpr = (float*)alloc((size_t)N * 128 * 4);
    float* pooled = (float*)alloc((size_t)G * 128 * 4);

    const int* send = edge_index;
    const int* recv = edge_index + E;

    // counting sort by receiver
    hipMemsetAsync(counts, 0, (size_t)N * 4, stream);
    hipMemsetAsync(cursor, 0, (size_t)N * 4, stream);
    k_hist<<<(E + 255) / 256, 256, 0, stream>>>(recv, counts, E);
    k_scan<<<1, 1024, 0, stream>>>(counts, offsets, N);
    k_scatter<<<(E + 255) / 256, 256, 0, stream>>>(send, recv, offsets, cursor, ss, sr, perm, E);
    k_permute_xe<<<(E * 4 + 255) / 256, 256, 0, stream>>>(x_edges, perm, xes, E);

    // embed
    k_embed1<<<(N * 64 + 255) / 256, 256, 0, stream>>>(x_nodes, emb_w1, emb_b1, t0, N);
    int gb = (N + 63) / 64;
    k_gemm128<<<gb, 256, 0, stream>>>(t0, emb_w2, nullptr, nullptr, emb_b2, N, 0, h, nullptr);

    for (int l = 0; l < L; ++l) {
        const float* ew1_l = ew1 + (size_t)l * 272 * 128;
        const float* ew2_l = ew2 + (size_t)l * 128 * 128;
        const float* nw1_l = nw1 + (size_t)l * 256 * 128;
        const float* nw2_l = nw2 + (size_t)l * 128 * 128;
        const float* eb1_l = eb1 + l * 128;
        const float* eb2_l = eb2 + l * 128;
        const float* nb1_l = nb1 + l * 128;
        const float* nb2_l = nb2 + l * 128;

        k_gemm_dual<<<gb, 256, 0, stream>>>(h, ew1_l, ew1_l + 128 * 128, Ps, Pr, N);
        hipMemsetAsync(aggr, 0, (size_t)N * 128 * 4, stream);
        k_edge<<<1536, 256, 0, stream>>>(Ps, Pr, xes, ss, sr, ew1_l + 256 * 128, eb1_l,
                                         ew2_l, eb2_l, aggr, E);
        k_gemm128<<<gb, 256, 0, stream>>>(h, nw1_l, aggr, nw1_l + 128 * 128, nb1_l, N, 1, t0, nullptr);
        k_gemm128<<<gb, 256, 0, stream>>>(t0, nw2_l, nullptr, nullptr, nb2_l, N, 0, h, nullptr);
    }

    // pre-readout + pooling + readout
    k_gemm128<<<gb, 256, 0, stream>>>(h, pr_w1, nullptr, nullptr, pr_b1, N, 1, t0, nullptr);
    k_gemm128<<<gb, 256, 0, stream>>>(t0, pr_w2, nullptr, nullptr, pr_b2, N, 0, nullptr, hpr);
    k_pool<<<G, 128, 0, stream>>>(hpr, batch, pooled, N);
    k_readout<<<G, 128, 0, stream>>>(pooled, ro_w1, ro_b1, ro_w2, ro_b2, (float*)d_out);
}

// Round 3
// 1547.398 us; speedup vs baseline: 1.1948x; 1.1948x over previous
//
#include <hip/hip_runtime.h>

// GNN forward for MI355X.
// - counting-sort edges by receiver; edge-MLP layer-1 decomposed into node-level
//   GEMMs Ps=h@Ws, Pr=h@Wr stored in SL layout (slot(c)=(c&15)*8+(c>>4)) so the
//   per-edge C-layout gather is ONE 16B load per row per matrix.
// - k_msg: t = Ps[s]+Pr[r]+xe@We+b1 in C-layout regs -> silu -> one LDS
//   transition -> msg = silu(t@W2+b2) via SWAPPED-operand MFMA (C col=edge) ->
//   4x 16B SL stores to msg[E,128] bf16. No atomics.
// - k_aggr: CSR contiguous segment sum over sorted msg rows -> aggr bf16.
//   Chunked if workspace can't hold full msg (seq read-modify-write at spans).
// - all weights pre-converted once to bf16 transposed [col][k] -> vector staging.

typedef short bf16x8 __attribute__((ext_vector_type(8)));
typedef float f32x4 __attribute__((ext_vector_type(4)));

union U8 { bf16x8 v; unsigned short u[8]; };

__device__ __forceinline__ float bf2f(unsigned short u) {
    union { unsigned int i; float f; } x; x.i = ((unsigned int)u) << 16; return x.f;
}
__device__ __forceinline__ unsigned short f2bf(float f) {
    union { float f; unsigned int i; } x; x.f = f;
    unsigned int r = x.i + 0x7FFFu + ((x.i >> 16) & 1u);
    return (unsigned short)(r >> 16);
}
__device__ __forceinline__ float siluf(float x) { return x / (1.0f + __expf(-x)); }

// ---------------- setup: counting sort by receiver ----------------
__global__ void k_hist(const int* __restrict__ recv, int* __restrict__ counts, int E) {
    int i = blockIdx.x * 256 + threadIdx.x;
    if (i < E) atomicAdd(&counts[recv[i]], 1);
}

__global__ void k_scan(const int* __restrict__ counts, int* __restrict__ offsets, int n) {
    __shared__ int buf[1024];
    __shared__ int carry;
    if (threadIdx.x == 0) carry = 0;
    __syncthreads();
    for (int base = 0; base < n; base += 1024) {
        int i = base + (int)threadIdx.x;
        int v = (i < n) ? counts[i] : 0;
        buf[threadIdx.x] = v;
        __syncthreads();
        for (int off = 1; off < 1024; off <<= 1) {
            int t = 0;
            if ((int)threadIdx.x >= off) t = buf[threadIdx.x - off];
            __syncthreads();
            if ((int)threadIdx.x >= off) buf[threadIdx.x] += t;
            __syncthreads();
        }
        if (i < n) offsets[i] = carry + buf[threadIdx.x] - v;
        __syncthreads();
        if (threadIdx.x == 0) carry += buf[1023];
        __syncthreads();
    }
    if (threadIdx.x == 0) offsets[n] = carry;
}

__global__ void k_scatter(const int* __restrict__ send, const int* __restrict__ recv,
                          const int* __restrict__ offsets, int* __restrict__ cursor,
                          int* __restrict__ ss, int* __restrict__ sr,
                          int* __restrict__ perm, int E) {
    int i = blockIdx.x * 256 + threadIdx.x;
    if (i < E) {
        int r = recv[i];
        int pos = offsets[r] + atomicAdd(&cursor[r], 1);
        ss[pos] = send[i];
        sr[pos] = r;
        perm[pos] = i;
    }
}

__global__ void k_permute_xe(const float* __restrict__ xe, const int* __restrict__ perm,
                             unsigned short* __restrict__ out, int E) {
    int t = blockIdx.x * 256 + threadIdx.x;
    if (t < E * 4) {
        int pos = t >> 2, q = t & 3;
        int e = perm[pos];
        float4 v = *(const float4*)(xe + (size_t)e * 16 + q * 4);
        ushort4 o;
        o.x = f2bf(v.x); o.y = f2bf(v.y); o.z = f2bf(v.z); o.w = f2bf(v.w);
        *(ushort4*)(out + (size_t)pos * 16 + q * 4) = o;
    }
}

// ---------------- weight pre-conversion: fp32 [K][128] -> bf16 [128][K] ----------------
struct WJob { const float* src; unsigned short* dst; int rows; };
struct WJobs { WJob j[31]; };

__global__ __launch_bounds__(256) void k_wconv(WJobs jobs) {
    WJob jb = jobs.j[blockIdx.x];
    int n = jb.rows * 128;
    for (int i = threadIdx.x; i < n; i += 256) {
        int k = i >> 7, c = i & 127;
        jb.dst[c * jb.rows + k] = f2bf(jb.src[i]);
    }
}

// ---------------- embed stage 1 (K=16, VALU) ----------------
__global__ __launch_bounds__(256) void k_embed1(const float* __restrict__ x,
                                                const float* __restrict__ w1,
                                                const float* __restrict__ b1,
                                                unsigned short* __restrict__ out, int N) {
    int idx = blockIdx.x * 256 + threadIdx.x;
    int n = idx >> 6, lane = idx & 63;
    if (n >= N) return;
    const float* xr = x + (size_t)n * 16;
    float xv[16];
#pragma unroll
    for (int k = 0; k < 16; k += 4) {
        float4 v = *(const float4*)(xr + k);
        xv[k] = v.x; xv[k + 1] = v.y; xv[k + 2] = v.z; xv[k + 3] = v.w;
    }
    int c0 = lane * 2;
    float a0 = b1[c0], a1 = b1[c0 + 1];
#pragma unroll
    for (int k = 0; k < 16; ++k) {
        float2 w = *(const float2*)(w1 + k * 128 + c0);
        a0 += xv[k] * w.x; a1 += xv[k] * w.y;
    }
    unsigned int pk = (unsigned int)f2bf(siluf(a0)) | ((unsigned int)f2bf(siluf(a1)) << 16);
    *(unsigned int*)(out + (size_t)n * 128 + c0) = pk;
}

// ---------------- node GEMM: out = act(A1@W1 [+ A2@W2] + b), 128 rows/block ----------------
__global__ __launch_bounds__(256, 3) void k_gemm128(
    const unsigned short* __restrict__ A1, const unsigned short* __restrict__ WT1,
    const unsigned short* __restrict__ A2, const unsigned short* __restrict__ WT2,
    const float* __restrict__ bias, int M, int act,
    unsigned short* __restrict__ out) {
    __shared__ unsigned short sW[128 * 136];
    int tid = threadIdx.x, lane = tid & 63, w = tid >> 6;
    int r0 = blockIdx.x * 128 + w * 32;
    int colb = lane & 15, kg = lane >> 4;
    f32x4 C[2][8];
#pragma unroll
    for (int rf = 0; rf < 2; ++rf)
#pragma unroll
        for (int cf = 0; cf < 8; ++cf) C[rf][cf] = (f32x4){0.f, 0.f, 0.f, 0.f};
    int npass = (WT2 != nullptr) ? 2 : 1;
    for (int pass = 0; pass < npass; ++pass) {
        const unsigned short* WT = pass ? WT2 : WT1;
        const unsigned short* A = pass ? A2 : A1;
        __syncthreads();
        for (int i = tid * 8; i < 16384; i += 2048)
            *(bf16x8*)(sW + (i >> 7) * 136 + (i & 127)) = *(const bf16x8*)(WT + i);
        __syncthreads();
        bf16x8 Af[2][4];
#pragma unroll
        for (int rf = 0; rf < 2; ++rf) {
            int row = r0 + rf * 16 + colb;
            bool rv = row < M;
#pragma unroll
            for (int ks = 0; ks < 4; ++ks) {
                if (rv) Af[rf][ks] = *(const bf16x8*)(A + (size_t)row * 128 + ks * 32 + kg * 8);
                else { U8 z; for (int i = 0; i < 8; ++i) z.u[i] = 0; Af[rf][ks] = z.v; }
            }
        }
#pragma unroll
        for (int ks = 0; ks < 4; ++ks) {
#pragma unroll
            for (int cf = 0; cf < 8; ++cf) {
                bf16x8 B = *(const bf16x8*)(sW + (colb + 16 * cf) * 136 + ks * 32 + kg * 8);
#pragma unroll
                for (int rf = 0; rf < 2; ++rf)
                    C[rf][cf] = __builtin_amdgcn_mfma_f32_16x16x32_bf16(Af[rf][ks], B, C[rf][cf], 0, 0, 0);
            }
        }
    }
#pragma unroll
    for (int rf = 0; rf < 2; ++rf) {
        int rb = r0 + rf * 16 + kg * 4;
#pragma unroll
        for (int cf = 0; cf < 8; ++cf) {
            int col = colb + 16 * cf;
            float bb = bias ? bias[col] : 0.f;
#pragma unroll
            for (int j = 0; j < 4; ++j) {
                int r = rb + j;
                if (r < M) {
                    float v = C[rf][cf][j] + bb;
                    if (act) v = siluf(v);
                    out[(size_t)r * 128 + col] = f2bf(v);
                }
            }
        }
    }
}

// ---------------- dual GEMM: Ps = A@Ws, Pr = A@Wr, outputs in SL layout ----------------
__global__ __launch_bounds__(256, 3) void k_gemm_dual(
    const unsigned short* __restrict__ A1, const unsigned short* __restrict__ WaT,
    const unsigned short* __restrict__ WbT,
    unsigned short* __restrict__ outA, unsigned short* __restrict__ outB, int M) {
    __shared__ unsigned short sW[128 * 136];
    int tid = threadIdx.x, lane = tid & 63, w = tid >> 6;
    int r0 = blockIdx.x * 128 + w * 32;
    int colb = lane & 15, kg = lane >> 4;
    bf16x8 Af[2][4];
#pragma unroll
    for (int rf = 0; rf < 2; ++rf) {
        int row = r0 + rf * 16 + colb;
        bool rv = row < M;
#pragma unroll
        for (int ks = 0; ks < 4; ++ks) {
            if (rv) Af[rf][ks] = *(const bf16x8*)(A1 + (size_t)row * 128 + ks * 32 + kg * 8);
            else { U8 z; for (int i = 0; i < 8; ++i) z.u[i] = 0; Af[rf][ks] = z.v; }
        }
    }
    for (int pass = 0; pass < 2; ++pass) {
        const unsigned short* WT = pass ? WbT : WaT;
        unsigned short* out = pass ? outB : outA;
        __syncthreads();
        for (int i = tid * 8; i < 16384; i += 2048)
            *(bf16x8*)(sW + (i >> 7) * 136 + (i & 127)) = *(const bf16x8*)(WT + i);
        __syncthreads();
        f32x4 C[2][8];
#pragma unroll
        for (int rf = 0; rf < 2; ++rf)
#pragma unroll
            for (int cf = 0; cf < 8; ++cf) C[rf][cf] = (f32x4){0.f, 0.f, 0.f, 0.f};
#pragma unroll
        for (int ks = 0; ks < 4; ++ks) {
#pragma unroll
            for (int cf = 0; cf < 8; ++cf) {
                bf16x8 B = *(const bf16x8*)(sW + (colb + 16 * cf) * 136 + ks * 32 + kg * 8);
#pragma unroll
                for (int rf = 0; rf < 2; ++rf)
                    C[rf][cf] = __builtin_amdgcn_mfma_f32_16x16x32_bf16(Af[rf][ks], B, C[rf][cf], 0, 0, 0);
            }
        }
        // SL-packed stores: slot(col)=(col&15)*8+(col>>4) -> lane packs cf 0..7 per row
#pragma unroll
        for (int rf = 0; rf < 2; ++rf) {
#pragma unroll
            for (int j = 0; j < 4; ++j) {
                int row = r0 + rf * 16 + kg * 4 + j;
                if (row < M) {
                    U8 o;
#pragma unroll
                    for (int cf = 0; cf < 8; ++cf) o.u[cf] = f2bf(C[rf][cf][j]);
                    *(bf16x8*)(out + (size_t)row * 128 + colb * 8) = o.v;
                }
            }
        }
    }
}

// ---------------- edge message kernel (no atomics, SL msg output) ----------------
__global__ __launch_bounds__(256, 3) void k_msg(
    const unsigned short* __restrict__ Ps, const unsigned short* __restrict__ Pr,
    const unsigned short* __restrict__ xes,
    const int* __restrict__ ss, const int* __restrict__ sr,
    const unsigned short* __restrict__ WeT, const float* __restrict__ b1,
    const unsigned short* __restrict__ W2T, const float* __restrict__ b2,
    unsigned short* __restrict__ msg, int ebase, int tile0, int tile1) {
    __shared__ unsigned short sW2[128 * 136];  // W2^T [col][k]
    __shared__ unsigned short sT[64 * 136];    // wave-private 16-row stripes
    int tid = threadIdx.x, lane = tid & 63, w = tid >> 6;
    int colb = lane & 15, kg = lane >> 4;
    int R0 = w * 16, rb = R0 + kg * 4;

    for (int i = tid * 8; i < 16384; i += 2048)
        *(bf16x8*)(sW2 + (i >> 7) * 136 + (i & 127)) = *(const bf16x8*)(W2T + i);
    // We^T bf16 [128][16]: B-fragments (zero-padded K 16->32)
    bf16x8 WeB[8];
#pragma unroll
    for (int cf = 0; cf < 8; ++cf) {
        if (kg < 2) WeB[cf] = *(const bf16x8*)(WeT + (colb + 16 * cf) * 16 + kg * 8);
        else { U8 z; for (int i = 0; i < 8; ++i) z.u[i] = 0; WeB[cf] = z.v; }
    }
    float b1v[8];
#pragma unroll
    for (int cf = 0; cf < 8; ++cf) b1v[cf] = b1[colb + 16 * cf];
    float b2r[32];
#pragma unroll
    for (int acf = 0; acf < 8; ++acf)
#pragma unroll
        for (int j = 0; j < 4; ++j) b2r[acf * 4 + j] = b2[acf * 16 + kg * 4 + j];
    __syncthreads();

    for (int tile = tile0 + blockIdx.x; tile < tile1; tile += gridDim.x) {
        int e0 = tile << 6;
        int4 s4 = *(const int4*)(ss + e0 + rb);
        int4 r4 = *(const int4*)(sr + e0 + rb);
        // MFMA-1: xc = xe @ We  (C: col=feature colb+16cf, row=edge rb+j)
        bf16x8 Axe;
        if (kg < 2) Axe = *(const bf16x8*)(xes + (size_t)(e0 + R0 + colb) * 16 + kg * 8);
        else { U8 z; for (int i = 0; i < 8; ++i) z.u[i] = 0; Axe = z.v; }
        f32x4 xc[8];
#pragma unroll
        for (int cf = 0; cf < 8; ++cf) {
            f32x4 z = {0.f, 0.f, 0.f, 0.f};
            xc[cf] = __builtin_amdgcn_mfma_f32_16x16x32_bf16(Axe, WeB[cf], z, 0, 0, 0);
        }
        // gather (SL 16B loads), combine, silu, one LDS write per element
#pragma unroll
        for (int j = 0; j < 4; ++j) {
            int s = (j == 0) ? s4.x : (j == 1) ? s4.y : (j == 2) ? s4.z : s4.w;
            int r = (j == 0) ? r4.x : (j == 1) ? r4.y : (j == 2) ? r4.z : r4.w;
            bf16x8 ps = *(const bf16x8*)(Ps + (size_t)s * 128 + colb * 8);
            bf16x8 pr = *(const bf16x8*)(Pr + (size_t)r * 128 + colb * 8);
            unsigned short* st = sT + (rb + j) * 136 + colb;
#pragma unroll
            for (int cf = 0; cf < 8; ++cf) {
                float v = bf2f((unsigned short)ps[cf]) + bf2f((unsigned short)pr[cf]) +
                          b1v[cf] + xc[cf][j];
                st[16 * cf] = f2bf(siluf(v));
            }
        }
        asm volatile("s_waitcnt lgkmcnt(0)" ::: "memory");
        __builtin_amdgcn_sched_barrier(0);
        // MFMA-2 swapped: D = W2^T(A) x t^T(B); C col=edge, row=out-feature
        bf16x8 Bt[4];
#pragma unroll
        for (int ks = 0; ks < 4; ++ks)
            Bt[ks] = *(const bf16x8*)(sT + (R0 + colb) * 136 + ks * 32 + kg * 8);
        f32x4 m[8];
#pragma unroll
        for (int acf = 0; acf < 8; ++acf)
            m[acf] = (f32x4){b2r[acf * 4], b2r[acf * 4 + 1], b2r[acf * 4 + 2], b2r[acf * 4 + 3]};
#pragma unroll
        for (int ks = 0; ks < 4; ++ks) {
#pragma unroll
            for (int acf = 0; acf < 8; ++acf) {
                bf16x8 Aw = *(const bf16x8*)(sW2 + (16 * acf + colb) * 136 + ks * 32 + kg * 8);
                m[acf] = __builtin_amdgcn_mfma_f32_16x16x32_bf16(Aw, Bt[ks], m[acf], 0, 0, 0);
            }
        }
        // msg in SL layout: edge e = e0+R0+colb; slot = (kg*4+j)*8 + acf
        size_t erow = (size_t)(e0 + R0 + colb - ebase) * 128;
#pragma unroll
        for (int j = 0; j < 4; ++j) {
            U8 o;
#pragma unroll
            for (int acf = 0; acf < 8; ++acf) o.u[acf] = f2bf(siluf(m[acf][j]));
            *(bf16x8*)(msg + erow + (kg * 4 + j) * 8) = o.v;
        }
    }
}

// ---------------- CSR aggregation over sorted msg (SL in, normal bf16 out) ----------------
__global__ __launch_bounds__(256) void k_aggr(
    const unsigned short* __restrict__ msg, const int* __restrict__ offsets,
    unsigned short* __restrict__ aggr, int e0, int e1, int N) {
    int gw = (blockIdx.x * 256 + threadIdx.x) >> 6;
    int lane = threadIdx.x & 63;
    int nw = (gridDim.x * 256) >> 6;
    int s = lane * 2;
    int c0 = (s >> 3) + 16 * (s & 7);  // inverse SL; c1 = c0 + 16
    for (int n = gw; n < N; n += nw) {
        int off0 = offsets[n], off1 = offsets[n + 1];
        int lo = off0 > e0 ? off0 : e0;
        int hi = off1 < e1 ? off1 : e1;
        if (e0 != 0 && lo >= hi) continue;
        float a0 = 0.f, a1 = 0.f;
        for (int e = lo; e < hi; ++e) {
            unsigned int v = *(const unsigned int*)(msg + (size_t)(e - e0) * 128 + s);
            a0 += bf2f((unsigned short)(v & 0xffff));
            a1 += bf2f((unsigned short)(v >> 16));
        }
        if (e0 != 0 && off0 < e0) {  // node spans chunk boundary: accumulate
            a0 += bf2f(aggr[(size_t)n * 128 + c0]);
            a1 += bf2f(aggr[(size_t)n * 128 + c0 + 16]);
        }
        aggr[(size_t)n * 128 + c0] = f2bf(a0);
        aggr[(size_t)n * 128 + c0 + 16] = f2bf(a1);
    }
}

// ---------------- pooling (batch sorted -> contiguous graph ranges) ----------------
__device__ __forceinline__ int lowerb(const int* a, int n, int v) {
    int lo = 0, hi = n;
    while (lo < hi) { int mid = (lo + hi) >> 1; if (a[mid] < v) lo = mid + 1; else hi = mid; }
    return lo;
}

__global__ __launch_bounds__(128) void k_pool(const unsigned short* __restrict__ hpr,
                                              const int* __restrict__ batch,
                                              float* __restrict__ pooled, int N) {
    __shared__ int s_lo, s_hi;
    int g = blockIdx.x;
    if (threadIdx.x == 0) { s_lo = lowerb(batch, N, g); s_hi = lowerb(batch, N, g + 1); }
    __syncthreads();
    int c = threadIdx.x;
    float acc = 0.f;
    for (int r = s_lo; r < s_hi; ++r) acc += bf2f(hpr[(size_t)r * 128 + c]);
    pooled[(size_t)g * 128 + c] = acc;
}

__global__ __launch_bounds__(128) void k_readout(const float* __restrict__ pooled,
                                                 const float* __restrict__ w1,
                                                 const float* __restrict__ b1,
                                                 const float* __restrict__ w2,
                                                 const float* __restrict__ b2,
                                                 float* __restrict__ out) {
    __shared__ float sp[128];
    __shared__ float sred[2];
    int g = blockIdx.x, t = threadIdx.x;
    sp[t] = pooled[(size_t)g * 128 + t];
    __syncthreads();
    float acc = b1[t];
    for (int k = 0; k < 128; ++k) acc += sp[k] * w1[k * 128 + t];
    float val = siluf(acc) * w2[t];
#pragma unroll
    for (int off = 32; off; off >>= 1) val += __shfl_down(val, off);
    if ((t & 63) == 0) sred[t >> 6] = val;
    __syncthreads();
    if (t == 0) out[g] = sred[0] + sred[1] + b2[0];
}

// ---------------- host launcher ----------------
extern "C" void kernel_launch(void* const* d_in, const int* in_sizes, int n_in,
                              void* d_out, int out_size, void* d_ws, size_t ws_size,
                              hipStream_t stream) {
    const float* x_nodes = (const float*)d_in[0];
    const float* x_edges = (const float*)d_in[1];
    const int* edge_index = (const int*)d_in[2];
    const int* batch = (const int*)d_in[3];
    const float* emb_w1 = (const float*)d_in[4];
    const float* emb_b1 = (const float*)d_in[5];
    const float* emb_w2 = (const float*)d_in[6];
    const float* emb_b2 = (const float*)d_in[7];
    const float* ew1 = (const float*)d_in[8];
    const float* eb1 = (const float*)d_in[9];
    const float* ew2 = (const float*)d_in[10];
    const float* eb2 = (const float*)d_in[11];
    const float* nw1 = (const float*)d_in[12];
    const float* nb1 = (const float*)d_in[13];
    const float* nw2 = (const float*)d_in[14];
    const float* nb2 = (const float*)d_in[15];
    const float* pr_w1 = (const float*)d_in[16];
    const float* pr_b1 = (const float*)d_in[17];
    const float* pr_w2 = (const float*)d_in[18];
    const float* pr_b2 = (const float*)d_in[19];
    const float* ro_w1 = (const float*)d_in[20];
    const float* ro_b1 = (const float*)d_in[21];
    const float* ro_w2 = (const float*)d_in[22];
    const float* ro_b2 = (const float*)d_in[23];

    const int N = in_sizes[0] / 16;
    const int E = in_sizes[1] / 16;
    const int G = 512;
    const int L = 4;

    char* p = (char*)d_ws;
    auto alloc = [&](size_t bytes) {
        void* r = p;
        p += (bytes + 255) & ~(size_t)255;
        return r;
    };
    int* counts = (int*)alloc((size_t)N * 4);
    int* cursor = (int*)alloc((size_t)N * 4);
    int* offsets = (int*)alloc((size_t)(N + 1) * 4);
    int* ss = (int*)alloc((size_t)E * 4);
    int* sr = (int*)alloc((size_t)E * 4);
    int* perm = (int*)alloc((size_t)E * 4);
    unsigned short* xes = (unsigned short*)alloc((size_t)E * 16 * 2);
    unsigned short* h = (unsigned short*)alloc((size_t)N * 128 * 2);
    unsigned short* t0 = (unsigned short*)alloc((size_t)N * 128 * 2);
    unsigned short* Ps = (unsigned short*)alloc((size_t)N * 128 * 2);
    unsigned short* Pr = (unsigned short*)alloc((size_t)N * 128 * 2);
    unsigned short* aggr = (unsigned short*)alloc((size_t)N * 128 * 2);
    unsigned short* hpr = (unsigned short*)alloc((size_t)N * 128 * 2);
    float* pooled = (float*)alloc((size_t)G * 128 * 4);

    // bf16-transposed weights
    const size_t WSZ = 128 * 128;  // elements
    unsigned short* wt_emb2 = (unsigned short*)alloc(WSZ * 2);
    unsigned short *wtWs[4], *wtWr[4], *wtWe[4], *wtW2[4], *wtN1a[4], *wtN1b[4], *wtN2[4];
    for (int l = 0; l < L; ++l) {
        wtWs[l] = (unsigned short*)alloc(WSZ * 2);
        wtWr[l] = (unsigned short*)alloc(WSZ * 2);
        wtWe[l] = (unsigned short*)alloc((size_t)16 * 128 * 2);
        wtW2[l] = (unsigned short*)alloc(WSZ * 2);
        wtN1a[l] = (unsigned short*)alloc(WSZ * 2);
        wtN1b[l] = (unsigned short*)alloc(WSZ * 2);
        wtN2[l] = (unsigned short*)alloc(WSZ * 2);
    }
    unsigned short* wt_pr1 = (unsigned short*)alloc(WSZ * 2);
    unsigned short* wt_pr2 = (unsigned short*)alloc(WSZ * 2);

    // msg chunk buffer = remaining workspace
    unsigned short* msg = (unsigned short*)p;
    size_t used = (size_t)(p - (char*)d_ws);
    size_t avail = ws_size > used ? ws_size - used : 0;
    long long chunkE = (long long)(avail / 256) & ~63LL;  // edges per chunk
    if (chunkE < 64) chunkE = 64;
    if (chunkE > E) chunkE = E;

    const int* send = edge_index;
    const int* recv = edge_index + E;

    // counting sort by receiver
    hipMemsetAsync(counts, 0, (size_t)N * 4, stream);
    hipMemsetAsync(cursor, 0, (size_t)N * 4, stream);
    k_hist<<<(E + 255) / 256, 256, 0, stream>>>(recv, counts, E);
    k_scan<<<1, 1024, 0, stream>>>(counts, offsets, N);
    k_scatter<<<(E + 255) / 256, 256, 0, stream>>>(send, recv, offsets, cursor, ss, sr, perm, E);
    k_permute_xe<<<(E * 4 + 255) / 256, 256, 0, stream>>>(x_edges, perm, xes, E);

    // weight conversion (31 jobs)
    WJobs jobs;
    int nj = 0;
    auto addj = [&](const float* s, unsigned short* d, int rows) {
        jobs.j[nj].src = s; jobs.j[nj].dst = d; jobs.j[nj].rows = rows; ++nj;
    };
    addj(emb_w2, wt_emb2, 128);
    for (int l = 0; l < L; ++l) {
        const float* ew1_l = ew1 + (size_t)l * 272 * 128;
        addj(ew1_l, wtWs[l], 128);
        addj(ew1_l + 128 * 128, wtWr[l], 128);
        addj(ew1_l + 256 * 128, wtWe[l], 16);
        addj(ew2 + (size_t)l * WSZ, wtW2[l], 128);
        const float* nw1_l = nw1 + (size_t)l * 256 * 128;
        addj(nw1_l, wtN1a[l], 128);
        addj(nw1_l + 128 * 128, wtN1b[l], 128);
        addj(nw2 + (size_t)l * WSZ, wtN2[l], 128);
    }
    addj(pr_w1, wt_pr1, 128);
    addj(pr_w2, wt_pr2, 128);
    k_wconv<<<nj, 256, 0, stream>>>(jobs);

    // embed
    k_embed1<<<(N * 64 + 255) / 256, 256, 0, stream>>>(x_nodes, emb_w1, emb_b1, t0, N);
    int gb = (N + 127) / 128;
    k_gemm128<<<gb, 256, 0, stream>>>(t0, wt_emb2, nullptr, nullptr, emb_b2, N, 0, h);

    for (int l = 0; l < L; ++l) {
        const float* eb1_l = eb1 + l * 128;
        const float* eb2_l = eb2 + l * 128;
        const float* nb1_l = nb1 + l * 128;
        const float* nb2_l = nb2 + l * 128;

        k_gemm_dual<<<gb, 256, 0, stream>>>(h, wtWs[l], wtWr[l], Ps, Pr, N);
        for (int ce0 = 0; ce0 < E; ce0 += (int)chunkE) {
            int ce1 = E < ce0 + (int)chunkE ? E : ce0 + (int)chunkE;
            int tA = ce0 >> 6, tB = ce1 >> 6;
            int ng = tB - tA; if (ng > 2048) ng = 2048;
            k_msg<<<ng, 256, 0, stream>>>(Ps, Pr, xes, ss, sr, wtWe[l], eb1_l,
                                          wtW2[l], eb2_l, msg, ce0, tA, tB);
            k_aggr<<<1024, 256, 0, stream>>>(msg, offsets, aggr, ce0, ce1, N);
        }
        k_gemm128<<<gb, 256, 0, stream>>>(h, wtN1a[l], aggr, wtN1b[l], nb1_l, N, 1, t0);
        k_gemm128<<<gb, 256, 0, stream>>>(t0, wtN2[l], nullptr, nullptr, nb2_l, N, 0, h);
    }

    // pre-readout + pooling + readout
    k_gemm128<<<gb, 256, 0, stream>>>(h, wt_pr1, nullptr, nullptr, pr_b1, N, 1, t0);
    k_gemm128<<<gb, 256, 0, stream>>>(t0, wt_pr2, nullptr, nullptr, pr_b2, N, 0, hpr);
    k_pool<<<G, 128, 0, stream>>>(hpr, batch, pooled, N);
    k_readout<<<G, 128, 0, stream>>>(pooled, ro_w1, ro_b1, ro_w2, ro_b2, (float*)d_out);
}

// Round 4
// 1526.494 us; speedup vs baseline: 1.2111x; 1.0137x over previous
//
#include <hip/hip_runtime.h>

// GNN forward for MI355X.
// - counting-sort edges by receiver; edge-MLP layer-1 decomposed into node-level
//   GEMMs Ps=h@Ws, Pr=h@Wr stored in SL layout (slot(c)=(c&15)*8+(c>>4)) so the
//   per-edge C-layout gather is ONE 16B load per row per matrix.
// - k_msg: t = Ps[s]+Pr[r]+xe@We+b1 in C-layout regs -> silu -> cvt_pk_bf16 ->
//   ONE ds_write_b128 per row into slot-ordered t-tile (K-permutation trick:
//   W2 staged with slot-permuted rows, so MFMA contraction over slots == feats)
//   -> msg = silu(t@W2+b2) via swapped-operand MFMA -> SL 16B stores. No atomics.
// - k_aggr: CSR contiguous segment sum over sorted msg rows -> aggr bf16.
// - weights pre-converted once to bf16 transposed [col][k] (W2: k slot-permuted).

typedef short bf16x8 __attribute__((ext_vector_type(8)));
typedef float f32x4 __attribute__((ext_vector_type(4)));

union U8 { bf16x8 v; unsigned short u[8]; unsigned int d[4]; };

__device__ __forceinline__ float bf2f(unsigned short u) {
    union { unsigned int i; float f; } x; x.i = ((unsigned int)u) << 16; return x.f;
}
__device__ __forceinline__ float u32lo2f(unsigned int d) {
    union { unsigned int i; float f; } x; x.i = d << 16; return x.f;
}
__device__ __forceinline__ float u32hi2f(unsigned int d) {
    union { unsigned int i; float f; } x; x.i = d & 0xffff0000u; return x.f;
}
__device__ __forceinline__ unsigned short f2bf(float f) {
    union { float f; unsigned int i; } x; x.f = f;
    unsigned int r = x.i + 0x7FFFu + ((x.i >> 16) & 1u);
    return (unsigned short)(r >> 16);
}
__device__ __forceinline__ unsigned int cvt_pk_bf16(float lo, float hi) {
    unsigned int r;
    asm("v_cvt_pk_bf16_f32 %0, %1, %2" : "=v"(r) : "v"(lo), "v"(hi));
    return r;
}
__device__ __forceinline__ float siluf(float x) { return x / (1.0f + __expf(-x)); }

// ---------------- setup: counting sort by receiver ----------------
__global__ void k_hist(const int* __restrict__ recv, int* __restrict__ counts, int E) {
    int i = blockIdx.x * 256 + threadIdx.x;
    if (i < E) atomicAdd(&counts[recv[i]], 1);
}

__global__ void k_scan(const int* __restrict__ counts, int* __restrict__ offsets, int n) {
    __shared__ int buf[1024];
    __shared__ int carry;
    if (threadIdx.x == 0) carry = 0;
    __syncthreads();
    for (int base = 0; base < n; base += 1024) {
        int i = base + (int)threadIdx.x;
        int v = (i < n) ? counts[i] : 0;
        buf[threadIdx.x] = v;
        __syncthreads();
        for (int off = 1; off < 1024; off <<= 1) {
            int t = 0;
            if ((int)threadIdx.x >= off) t = buf[threadIdx.x - off];
            __syncthreads();
            if ((int)threadIdx.x >= off) buf[threadIdx.x] += t;
            __syncthreads();
        }
        if (i < n) offsets[i] = carry + buf[threadIdx.x] - v;
        __syncthreads();
        if (threadIdx.x == 0) carry += buf[1023];
        __syncthreads();
    }
    if (threadIdx.x == 0) offsets[n] = carry;
}

__global__ void k_scatter(const int* __restrict__ send, const int* __restrict__ recv,
                          const int* __restrict__ offsets, int* __restrict__ cursor,
                          int* __restrict__ ss, int* __restrict__ sr,
                          int* __restrict__ perm, int E) {
    int i = blockIdx.x * 256 + threadIdx.x;
    if (i < E) {
        int r = recv[i];
        int pos = offsets[r] + atomicAdd(&cursor[r], 1);
        ss[pos] = send[i];
        sr[pos] = r;
        perm[pos] = i;
    }
}

__global__ void k_permute_xe(const float* __restrict__ xe, const int* __restrict__ perm,
                             unsigned short* __restrict__ out, int E) {
    int t = blockIdx.x * 256 + threadIdx.x;
    if (t < E * 4) {
        int pos = t >> 2, q = t & 3;
        int e = perm[pos];
        float4 v = *(const float4*)(xe + (size_t)e * 16 + q * 4);
        ushort4 o;
        o.x = f2bf(v.x); o.y = f2bf(v.y); o.z = f2bf(v.z); o.w = f2bf(v.w);
        *(ushort4*)(out + (size_t)pos * 16 + q * 4) = o;
    }
}

// ---------------- weight pre-conversion: fp32 [K][128] -> bf16 [128][K] ----------------
// perm!=0: K-dim stored in SL-slot order (feat(slot) = (slot>>3) + 16*(slot&7))
struct WJob { const float* src; unsigned short* dst; int rows; int perm; };
struct WJobs { WJob j[31]; };

__global__ __launch_bounds__(256) void k_wconv(WJobs jobs) {
    WJob jb = jobs.j[blockIdx.x];
    int n = jb.rows * 128;
    if (jb.perm) {
        for (int i = threadIdx.x; i < n; i += 256) {
            int c = i >> 7, slot = i & 127;
            int feat = (slot >> 3) + 16 * (slot & 7);
            jb.dst[c * 128 + slot] = f2bf(jb.src[feat * 128 + c]);
        }
    } else {
        for (int i = threadIdx.x; i < n; i += 256) {
            int k = i >> 7, c = i & 127;
            jb.dst[c * jb.rows + k] = f2bf(jb.src[i]);
        }
    }
}

// ---------------- embed stage 1 (K=16, VALU) ----------------
__global__ __launch_bounds__(256) void k_embed1(const float* __restrict__ x,
                                                const float* __restrict__ w1,
                                                const float* __restrict__ b1,
                                                unsigned short* __restrict__ out, int N) {
    int idx = blockIdx.x * 256 + threadIdx.x;
    int n = idx >> 6, lane = idx & 63;
    if (n >= N) return;
    const float* xr = x + (size_t)n * 16;
    float xv[16];
#pragma unroll
    for (int k = 0; k < 16; k += 4) {
        float4 v = *(const float4*)(xr + k);
        xv[k] = v.x; xv[k + 1] = v.y; xv[k + 2] = v.z; xv[k + 3] = v.w;
    }
    int c0 = lane * 2;
    float a0 = b1[c0], a1 = b1[c0 + 1];
#pragma unroll
    for (int k = 0; k < 16; ++k) {
        float2 w = *(const float2*)(w1 + k * 128 + c0);
        a0 += xv[k] * w.x; a1 += xv[k] * w.y;
    }
    *(unsigned int*)(out + (size_t)n * 128 + c0) = cvt_pk_bf16(siluf(a0), siluf(a1));
}

// ---------------- node GEMM: out = act(A1@W1 [+ A2@W2] + b), 128 rows/block ----------------
__global__ __launch_bounds__(256, 3) void k_gemm128(
    const unsigned short* __restrict__ A1, const unsigned short* __restrict__ WT1,
    const unsigned short* __restrict__ A2, const unsigned short* __restrict__ WT2,
    const float* __restrict__ bias, int M, int act,
    unsigned short* __restrict__ out) {
    __shared__ unsigned short sW[128 * 136];
    int tid = threadIdx.x, lane = tid & 63, w = tid >> 6;
    int r0 = blockIdx.x * 128 + w * 32;
    int colb = lane & 15, kg = lane >> 4;
    f32x4 C[2][8];
#pragma unroll
    for (int rf = 0; rf < 2; ++rf)
#pragma unroll
        for (int cf = 0; cf < 8; ++cf) C[rf][cf] = (f32x4){0.f, 0.f, 0.f, 0.f};
    int npass = (WT2 != nullptr) ? 2 : 1;
    for (int pass = 0; pass < npass; ++pass) {
        const unsigned short* WT = pass ? WT2 : WT1;
        const unsigned short* A = pass ? A2 : A1;
        __syncthreads();
        for (int i = tid * 8; i < 16384; i += 2048)
            *(bf16x8*)(sW + (i >> 7) * 136 + (i & 127)) = *(const bf16x8*)(WT + i);
        __syncthreads();
        bf16x8 Af[2][4];
#pragma unroll
        for (int rf = 0; rf < 2; ++rf) {
            int row = r0 + rf * 16 + colb;
            bool rv = row < M;
#pragma unroll
            for (int ks = 0; ks < 4; ++ks) {
                if (rv) Af[rf][ks] = *(const bf16x8*)(A + (size_t)row * 128 + ks * 32 + kg * 8);
                else { U8 z; for (int i = 0; i < 8; ++i) z.u[i] = 0; Af[rf][ks] = z.v; }
            }
        }
#pragma unroll
        for (int ks = 0; ks < 4; ++ks) {
#pragma unroll
            for (int cf = 0; cf < 8; ++cf) {
                bf16x8 B = *(const bf16x8*)(sW + (colb + 16 * cf) * 136 + ks * 32 + kg * 8);
#pragma unroll
                for (int rf = 0; rf < 2; ++rf)
                    C[rf][cf] = __builtin_amdgcn_mfma_f32_16x16x32_bf16(Af[rf][ks], B, C[rf][cf], 0, 0, 0);
            }
        }
    }
#pragma unroll
    for (int rf = 0; rf < 2; ++rf) {
        int rb = r0 + rf * 16 + kg * 4;
#pragma unroll
        for (int cf = 0; cf < 8; ++cf) {
            int col = colb + 16 * cf;
            float bb = bias ? bias[col] : 0.f;
#pragma unroll
            for (int j = 0; j < 4; ++j) {
                int r = rb + j;
                if (r < M) {
                    float v = C[rf][cf][j] + bb;
                    if (act) v = siluf(v);
                    out[(size_t)r * 128 + col] = f2bf(v);
                }
            }
        }
    }
}

// ---------------- dual GEMM: Ps = A@Ws, Pr = A@Wr, outputs in SL layout ----------------
__global__ __launch_bounds__(256, 3) void k_gemm_dual(
    const unsigned short* __restrict__ A1, const unsigned short* __restrict__ WaT,
    const unsigned short* __restrict__ WbT,
    unsigned short* __restrict__ outA, unsigned short* __restrict__ outB, int M) {
    __shared__ unsigned short sW[128 * 136];
    int tid = threadIdx.x, lane = tid & 63, w = tid >> 6;
    int r0 = blockIdx.x * 128 + w * 32;
    int colb = lane & 15, kg = lane >> 4;
    bf16x8 Af[2][4];
#pragma unroll
    for (int rf = 0; rf < 2; ++rf) {
        int row = r0 + rf * 16 + colb;
        bool rv = row < M;
#pragma unroll
        for (int ks = 0; ks < 4; ++ks) {
            if (rv) Af[rf][ks] = *(const bf16x8*)(A1 + (size_t)row * 128 + ks * 32 + kg * 8);
            else { U8 z; for (int i = 0; i < 8; ++i) z.u[i] = 0; Af[rf][ks] = z.v; }
        }
    }
    for (int pass = 0; pass < 2; ++pass) {
        const unsigned short* WT = pass ? WbT : WaT;
        unsigned short* out = pass ? outB : outA;
        __syncthreads();
        for (int i = tid * 8; i < 16384; i += 2048)
            *(bf16x8*)(sW + (i >> 7) * 136 + (i & 127)) = *(const bf16x8*)(WT + i);
        __syncthreads();
        f32x4 C[2][8];
#pragma unroll
        for (int rf = 0; rf < 2; ++rf)
#pragma unroll
            for (int cf = 0; cf < 8; ++cf) C[rf][cf] = (f32x4){0.f, 0.f, 0.f, 0.f};
#pragma unroll
        for (int ks = 0; ks < 4; ++ks) {
#pragma unroll
            for (int cf = 0; cf < 8; ++cf) {
                bf16x8 B = *(const bf16x8*)(sW + (colb + 16 * cf) * 136 + ks * 32 + kg * 8);
#pragma unroll
                for (int rf = 0; rf < 2; ++rf)
                    C[rf][cf] = __builtin_amdgcn_mfma_f32_16x16x32_bf16(Af[rf][ks], B, C[rf][cf], 0, 0, 0);
            }
        }
        // SL-packed stores: slot(col)=(col&15)*8+(col>>4)
#pragma unroll
        for (int rf = 0; rf < 2; ++rf) {
#pragma unroll
            for (int j = 0; j < 4; ++j) {
                int row = r0 + rf * 16 + kg * 4 + j;
                if (row < M) {
                    U8 o;
#pragma unroll
                    for (int q = 0; q < 4; ++q)
                        o.d[q] = cvt_pk_bf16(C[rf][2 * q][j], C[rf][2 * q + 1][j]);
                    *(bf16x8*)(out + (size_t)row * 128 + colb * 8) = o.v;
                }
            }
        }
    }
}

// ---------------- edge message kernel (no atomics, SL msg output) ----------------
__global__ __launch_bounds__(256, 3) void k_msg(
    const unsigned short* __restrict__ Ps, const unsigned short* __restrict__ Pr,
    const unsigned short* __restrict__ xes,
    const int* __restrict__ ss, const int* __restrict__ sr,
    const unsigned short* __restrict__ WeT, const float* __restrict__ b1,
    const unsigned short* __restrict__ W2T, const float* __restrict__ b2,
    unsigned short* __restrict__ msg, int ebase, int tile0, int tile1) {
    __shared__ unsigned short sW2[128 * 136];  // W2^T [col][slot] (K slot-permuted)
    __shared__ unsigned short sT[64 * 136];    // t tile, [edge][slot], wave-private stripes
    int tid = threadIdx.x, lane = tid & 63, w = tid >> 6;
    int colb = lane & 15, kg = lane >> 4;
    int R0 = w * 16, rb = R0 + kg * 4;

    for (int i = tid * 8; i < 16384; i += 2048)
        *(bf16x8*)(sW2 + (i >> 7) * 136 + (i & 127)) = *(const bf16x8*)(W2T + i);
    // We^T bf16 [128][16]: B-fragments (zero-padded K 16->32)
    bf16x8 WeB[8];
#pragma unroll
    for (int cf = 0; cf < 8; ++cf) {
        if (kg < 2) WeB[cf] = *(const bf16x8*)(WeT + (colb + 16 * cf) * 16 + kg * 8);
        else { U8 z; for (int i = 0; i < 8; ++i) z.u[i] = 0; WeB[cf] = z.v; }
    }
    float b1v[8];
#pragma unroll
    for (int cf = 0; cf < 8; ++cf) b1v[cf] = b1[colb + 16 * cf];
    float b2r[32];
#pragma unroll
    for (int acf = 0; acf < 8; ++acf)
#pragma unroll
        for (int j = 0; j < 4; ++j) b2r[acf * 4 + j] = b2[acf * 16 + kg * 4 + j];
    __syncthreads();

    for (int tile = tile0 + blockIdx.x; tile < tile1; tile += gridDim.x) {
        int e0 = tile << 6;
        int4 s4 = *(const int4*)(ss + e0 + rb);
        int4 r4 = *(const int4*)(sr + e0 + rb);
        // issue all gathers early (SL 16B rows)
        U8 ps0, ps1, ps2, ps3, pr0, pr1, pr2, pr3;
        ps0.v = *(const bf16x8*)(Ps + (size_t)s4.x * 128 + colb * 8);
        ps1.v = *(const bf16x8*)(Ps + (size_t)s4.y * 128 + colb * 8);
        ps2.v = *(const bf16x8*)(Ps + (size_t)s4.z * 128 + colb * 8);
        ps3.v = *(const bf16x8*)(Ps + (size_t)s4.w * 128 + colb * 8);
        pr0.v = *(const bf16x8*)(Pr + (size_t)r4.x * 128 + colb * 8);
        pr1.v = *(const bf16x8*)(Pr + (size_t)r4.y * 128 + colb * 8);
        pr2.v = *(const bf16x8*)(Pr + (size_t)r4.z * 128 + colb * 8);
        pr3.v = *(const bf16x8*)(Pr + (size_t)r4.w * 128 + colb * 8);
        // MFMA-1: xc = xe @ We  (C: col=feature colb+16cf, row=edge rb+j)
        bf16x8 Axe;
        if (kg < 2) Axe = *(const bf16x8*)(xes + (size_t)(e0 + R0 + colb) * 16 + kg * 8);
        else { U8 z; for (int i = 0; i < 8; ++i) z.u[i] = 0; Axe = z.v; }
        f32x4 xc[8];
#pragma unroll
        for (int cf = 0; cf < 8; ++cf) {
            f32x4 z = {0.f, 0.f, 0.f, 0.f};
            xc[cf] = __builtin_amdgcn_mfma_f32_16x16x32_bf16(Axe, WeB[cf], z, 0, 0, 0);
        }
        // combine + silu + cvt_pk -> ONE b128 write per row (slot-ordered t)
#pragma unroll
        for (int j = 0; j < 4; ++j) {
            const U8& ps = (j == 0) ? ps0 : (j == 1) ? ps1 : (j == 2) ? ps2 : ps3;
            const U8& pr = (j == 0) ? pr0 : (j == 1) ? pr1 : (j == 2) ? pr2 : pr3;
            U8 o;
#pragma unroll
            for (int q = 0; q < 4; ++q) {
                float v0 = u32lo2f(ps.d[q]) + u32lo2f(pr.d[q]) + b1v[2 * q] + xc[2 * q][j];
                float v1 = u32hi2f(ps.d[q]) + u32hi2f(pr.d[q]) + b1v[2 * q + 1] + xc[2 * q + 1][j];
                o.d[q] = cvt_pk_bf16(siluf(v0), siluf(v1));
            }
            *(bf16x8*)(sT + (rb + j) * 136 + colb * 8) = o.v;
        }
        // wave-local write->read ordering (no cross-wave sharing of sT rows)
        asm volatile("s_waitcnt lgkmcnt(0)" ::: "memory");
        __builtin_amdgcn_sched_barrier(0);
        // MFMA-2 swapped: D = W2^T(A) x t^T(B); C col=edge, row=out-feature
        bf16x8 Bt[4];
#pragma unroll
        for (int ks = 0; ks < 4; ++ks)
            Bt[ks] = *(const bf16x8*)(sT + (R0 + colb) * 136 + ks * 32 + kg * 8);
        f32x4 m[8];
#pragma unroll
        for (int acf = 0; acf < 8; ++acf)
            m[acf] = (f32x4){b2r[acf * 4], b2r[acf * 4 + 1], b2r[acf * 4 + 2], b2r[acf * 4 + 3]};
#pragma unroll
        for (int ks = 0; ks < 4; ++ks) {
#pragma unroll
            for (int acf = 0; acf < 8; ++acf) {
                bf16x8 Aw = *(const bf16x8*)(sW2 + (16 * acf + colb) * 136 + ks * 32 + kg * 8);
                m[acf] = __builtin_amdgcn_mfma_f32_16x16x32_bf16(Aw, Bt[ks], m[acf], 0, 0, 0);
            }
        }
        // msg in SL layout: edge e = e0+R0+colb; slot = (kg*4+j)*8 + acf
        size_t erow = (size_t)(e0 + R0 + colb - ebase) * 128;
#pragma unroll
        for (int j = 0; j < 4; ++j) {
            U8 o;
#pragma unroll
            for (int q = 0; q < 4; ++q)
                o.d[q] = cvt_pk_bf16(siluf(m[2 * q][j]), siluf(m[2 * q + 1][j]));
            *(bf16x8*)(msg + erow + (kg * 4 + j) * 8) = o.v;
        }
    }
}

// ---------------- CSR aggregation over sorted msg (SL in, normal bf16 out) ----------------
__global__ __launch_bounds__(256) void k_aggr(
    const unsigned short* __restrict__ msg, const int* __restrict__ offsets,
    unsigned short* __restrict__ aggr, int e0, int e1, int N) {
    int gw = (blockIdx.x * 256 + threadIdx.x) >> 6;
    int lane = threadIdx.x & 63;
    int nw = (gridDim.x * 256) >> 6;
    int s = lane * 2;
    int c0 = (s >> 3) + 16 * (s & 7);  // inverse SL; c1 = c0 + 16
    for (int n = gw; n < N; n += nw) {
        int off0 = offsets[n], off1 = offsets[n + 1];
        int lo = off0 > e0 ? off0 : e0;
        int hi = off1 < e1 ? off1 : e1;
        if (e0 != 0 && lo >= hi) continue;
        float a0 = 0.f, a1 = 0.f;
        for (int e = lo; e < hi; ++e) {
            unsigned int v = *(const unsigned int*)(msg + (size_t)(e - e0) * 128 + s);
            a0 += u32lo2f(v);
            a1 += u32hi2f(v);
        }
        if (e0 != 0 && off0 < e0) {  // node spans chunk boundary: accumulate
            a0 += bf2f(aggr[(size_t)n * 128 + c0]);
            a1 += bf2f(aggr[(size_t)n * 128 + c0 + 16]);
        }
        aggr[(size_t)n * 128 + c0] = f2bf(a0);
        aggr[(size_t)n * 128 + c0 + 16] = f2bf(a1);
    }
}

// ---------------- pooling (batch sorted -> contiguous graph ranges) ----------------
__device__ __forceinline__ int lowerb(const int* a, int n, int v) {
    int lo = 0, hi = n;
    while (lo < hi) { int mid = (lo + hi) >> 1; if (a[mid] < v) lo = mid + 1; else hi = mid; }
    return lo;
}

__global__ __launch_bounds__(128) void k_pool(const unsigned short* __restrict__ hpr,
                                              const int* __restrict__ batch,
                                              float* __restrict__ pooled, int N) {
    __shared__ int s_lo, s_hi;
    int g = blockIdx.x;
    if (threadIdx.x == 0) { s_lo = lowerb(batch, N, g); s_hi = lowerb(batch, N, g + 1); }
    __syncthreads();
    int c = threadIdx.x;
    float acc = 0.f;
    for (int r = s_lo; r < s_hi; ++r) acc += bf2f(hpr[(size_t)r * 128 + c]);
    pooled[(size_t)g * 128 + c] = acc;
}

__global__ __launch_bounds__(128) void k_readout(const float* __restrict__ pooled,
                                                 const float* __restrict__ w1,
                                                 const float* __restrict__ b1,
                                                 const float* __restrict__ w2,
                                                 const float* __restrict__ b2,
                                                 float* __restrict__ out) {
    __shared__ float sp[128];
    __shared__ float sred[2];
    int g = blockIdx.x, t = threadIdx.x;
    sp[t] = pooled[(size_t)g * 128 + t];
    __syncthreads();
    float acc = b1[t];
    for (int k = 0; k < 128; ++k) acc += sp[k] * w1[k * 128 + t];
    float val = siluf(acc) * w2[t];
#pragma unroll
    for (int off = 32; off; off >>= 1) val += __shfl_down(val, off);
    if ((t & 63) == 0) sred[t >> 6] = val;
    __syncthreads();
    if (t == 0) out[g] = sred[0] + sred[1] + b2[0];
}

// ---------------- host launcher ----------------
extern "C" void kernel_launch(void* const* d_in, const int* in_sizes, int n_in,
                              void* d_out, int out_size, void* d_ws, size_t ws_size,
                              hipStream_t stream) {
    const float* x_nodes = (const float*)d_in[0];
    const float* x_edges = (const float*)d_in[1];
    const int* edge_index = (const int*)d_in[2];
    const int* batch = (const int*)d_in[3];
    const float* emb_w1 = (const float*)d_in[4];
    const float* emb_b1 = (const float*)d_in[5];
    const float* emb_w2 = (const float*)d_in[6];
    const float* emb_b2 = (const float*)d_in[7];
    const float* ew1 = (const float*)d_in[8];
    const float* eb1 = (const float*)d_in[9];
    const float* ew2 = (const float*)d_in[10];
    const float* eb2 = (const float*)d_in[11];
    const float* nw1 = (const float*)d_in[12];
    const float* nb1 = (const float*)d_in[13];
    const float* nw2 = (const float*)d_in[14];
    const float* nb2 = (const float*)d_in[15];
    const float* pr_w1 = (const float*)d_in[16];
    const float* pr_b1 = (const float*)d_in[17];
    const float* pr_w2 = (const float*)d_in[18];
    const float* pr_b2 = (const float*)d_in[19];
    const float* ro_w1 = (const float*)d_in[20];
    const float* ro_b1 = (const float*)d_in[21];
    const float* ro_w2 = (const float*)d_in[22];
    const float* ro_b2 = (const float*)d_in[23];

    const int N = in_sizes[0] / 16;
    const int E = in_sizes[1] / 16;
    const int G = 512;
    const int L = 4;

    char* p = (char*)d_ws;
    auto alloc = [&](size_t bytes) {
        void* r = p;
        p += (bytes + 255) & ~(size_t)255;
        return r;
    };
    int* counts = (int*)alloc((size_t)N * 4);
    int* cursor = (int*)alloc((size_t)N * 4);
    int* offsets = (int*)alloc((size_t)(N + 1) * 4);
    int* ss = (int*)alloc((size_t)E * 4);
    int* sr = (int*)alloc((size_t)E * 4);
    int* perm = (int*)alloc((size_t)E * 4);
    unsigned short* xes = (unsigned short*)alloc((size_t)E * 16 * 2);
    unsigned short* h = (unsigned short*)alloc((size_t)N * 128 * 2);
    unsigned short* t0 = (unsigned short*)alloc((size_t)N * 128 * 2);
    unsigned short* Ps = (unsigned short*)alloc((size_t)N * 128 * 2);
    unsigned short* Pr = (unsigned short*)alloc((size_t)N * 128 * 2);
    unsigned short* aggr = (unsigned short*)alloc((size_t)N * 128 * 2);
    unsigned short* hpr = (unsigned short*)alloc((size_t)N * 128 * 2);
    float* pooled = (float*)alloc((size_t)G * 128 * 4);

    // bf16-transposed weights
    const size_t WSZ = 128 * 128;  // elements
    unsigned short* wt_emb2 = (unsigned short*)alloc(WSZ * 2);
    unsigned short *wtWs[4], *wtWr[4], *wtWe[4], *wtW2[4], *wtN1a[4], *wtN1b[4], *wtN2[4];
    for (int l = 0; l < L; ++l) {
        wtWs[l] = (unsigned short*)alloc(WSZ * 2);
        wtWr[l] = (unsigned short*)alloc(WSZ * 2);
        wtWe[l] = (unsigned short*)alloc((size_t)16 * 128 * 2);
        wtW2[l] = (unsigned short*)alloc(WSZ * 2);
        wtN1a[l] = (unsigned short*)alloc(WSZ * 2);
        wtN1b[l] = (unsigned short*)alloc(WSZ * 2);
        wtN2[l] = (unsigned short*)alloc(WSZ * 2);
    }
    unsigned short* wt_pr1 = (unsigned short*)alloc(WSZ * 2);
    unsigned short* wt_pr2 = (unsigned short*)alloc(WSZ * 2);

    // msg chunk buffer = remaining workspace
    unsigned short* msg = (unsigned short*)p;
    size_t used = (size_t)(p - (char*)d_ws);
    size_t avail = ws_size > used ? ws_size - used : 0;
    long long chunkE = (long long)(avail / 256) & ~63LL;  // edges per chunk
    if (chunkE < 64) chunkE = 64;
    if (chunkE > E) chunkE = E;

    const int* send = edge_index;
    const int* recv = edge_index + E;

    // counting sort by receiver
    hipMemsetAsync(counts, 0, (size_t)N * 4, stream);
    hipMemsetAsync(cursor, 0, (size_t)N * 4, stream);
    k_hist<<<(E + 255) / 256, 256, 0, stream>>>(recv, counts, E);
    k_scan<<<1, 1024, 0, stream>>>(counts, offsets, N);
    k_scatter<<<(E + 255) / 256, 256, 0, stream>>>(send, recv, offsets, cursor, ss, sr, perm, E);
    k_permute_xe<<<(E * 4 + 255) / 256, 256, 0, stream>>>(x_edges, perm, xes, E);

    // weight conversion (31 jobs)
    WJobs jobs;
    int nj = 0;
    auto addj = [&](const float* s, unsigned short* d, int rows, int pm) {
        jobs.j[nj].src = s; jobs.j[nj].dst = d; jobs.j[nj].rows = rows; jobs.j[nj].perm = pm; ++nj;
    };
    addj(emb_w2, wt_emb2, 128, 0);
    for (int l = 0; l < L; ++l) {
        const float* ew1_l = ew1 + (size_t)l * 272 * 128;
        addj(ew1_l, wtWs[l], 128, 0);
        addj(ew1_l + 128 * 128, wtWr[l], 128, 0);
        addj(ew1_l + 256 * 128, wtWe[l], 16, 0);
        addj(ew2 + (size_t)l * WSZ, wtW2[l], 128, 1);  // slot-permuted K
        const float* nw1_l = nw1 + (size_t)l * 256 * 128;
        addj(nw1_l, wtN1a[l], 128, 0);
        addj(nw1_l + 128 * 128, wtN1b[l], 128, 0);
        addj(nw2 + (size_t)l * WSZ, wtN2[l], 128, 0);
    }
    addj(pr_w1, wt_pr1, 128, 0);
    addj(pr_w2, wt_pr2, 128, 0);
    k_wconv<<<nj, 256, 0, stream>>>(jobs);

    // embed
    k_embed1<<<(N * 64 + 255) / 256, 256, 0, stream>>>(x_nodes, emb_w1, emb_b1, t0, N);
    int gb = (N + 127) / 128;
    k_gemm128<<<gb, 256, 0, stream>>>(t0, wt_emb2, nullptr, nullptr, emb_b2, N, 0, h);

    for (int l = 0; l < L; ++l) {
        const float* eb1_l = eb1 + l * 128;
        const float* eb2_l = eb2 + l * 128;
        const float* nb1_l = nb1 + l * 128;
        const float* nb2_l = nb2 + l * 128;

        k_gemm_dual<<<gb, 256, 0, stream>>>(h, wtWs[l], wtWr[l], Ps, Pr, N);
        for (int ce0 = 0; ce0 < E; ce0 += (int)chunkE) {
            int ce1 = E < ce0 + (int)chunkE ? E : ce0 + (int)chunkE;
            int tA = ce0 >> 6, tB = ce1 >> 6;
            int ng = tB - tA; if (ng > 2048) ng = 2048;
            k_msg<<<ng, 256, 0, stream>>>(Ps, Pr, xes, ss, sr, wtWe[l], eb1_l,
                                          wtW2[l], eb2_l, msg, ce0, tA, tB);
            k_aggr<<<1024, 256, 0, stream>>>(msg, offsets, aggr, ce0, ce1, N);
        }
        k_gemm128<<<gb, 256, 0, stream>>>(h, wtN1a[l], aggr, wtN1b[l], nb1_l, N, 1, t0);
        k_gemm128<<<gb, 256, 0, stream>>>(t0, wtN2[l], nullptr, nullptr, nb2_l, N, 0, h);
    }

    // pre-readout + pooling + readout
    k_gemm128<<<gb, 256, 0, stream>>>(h, wt_pr1, nullptr, nullptr, pr_b1, N, 1, t0);
    k_gemm128<<<gb, 256, 0, stream>>>(t0, wt_pr2, nullptr, nullptr, pr_b2, N, 0, hpr);
    k_pool<<<G, 128, 0, stream>>>(hpr, batch, pooled, N);
    k_readout<<<G, 128, 0, stream>>>(pooled, ro_w1, ro_b1, ro_w2, ro_b2, (float*)d_out);
}